// Round 9
// baseline (297.525 us; speedup 1.0000x reference)
//
#include <hip/hip_runtime.h>
#include <hip/hip_fp16.h>

#define DEV __device__ __forceinline__

using half8 = __attribute__((ext_vector_type(8))) _Float16;
using half4 = __attribute__((ext_vector_type(4))) _Float16;
using f32x4 = __attribute__((ext_vector_type(4))) float;

// async global->LDS, 16B per lane. LDS dest is wave-uniform base + lane*16B.
DEV void gload_lds16(const void* g, void* l) {
  __builtin_amdgcn_global_load_lds((const __attribute__((address_space(1))) unsigned int*)g,
                                   (__attribute__((address_space(3))) unsigned int*)l,
                                   16, 0, 0);
}

DEV f32x4 mfma16x32(half8 a, half8 b, f32x4 c) {
  return __builtin_amdgcn_mfma_f32_16x16x32_f16(a, b, c, 0, 0, 0);
}

DEV void conv2048(const float* __restrict__ s, _Float16* __restrict__ d, int t) {
  int i = t * 8;
  float4 a = *(const float4*)(s + i);
  float4 b = *(const float4*)(s + i + 4);
  half8 h;
  h[0] = (_Float16)a.x; h[1] = (_Float16)a.y; h[2] = (_Float16)a.z; h[3] = (_Float16)a.w;
  h[4] = (_Float16)b.x; h[5] = (_Float16)b.y; h[6] = (_Float16)b.z; h[7] = (_Float16)b.w;
  *(half8*)(d + i) = h;
}

DEV void rp_body(const float* __restrict__ Wlin, const float* __restrict__ wg,
                 float* __restrict__ rp, int s, int t) {
  if (t >= 144) return;
  int rs = s / 12, cs = s % 12, rt = t / 12, ct = t % 12;
  float dx = (cs - ct) / 12.f, dy = (rs - rt) / 12.f;
  float ax = (dx > 0.f) ? 0.5f : (dx < 0.f ? -0.5f : 0.f);
  float ay = (dy > 0.f) ? 0.5f : (dy < 0.f ? -0.5f : 0.f);
  float lx = fabsf(logf(fabsf(dx) + 0.5f));
  float ly = fabsf(logf(fabsf(dy) + 0.5f));
  float a0 = 0.f, a1 = 0.f, a2 = 0.f, a3 = 0.f;
  const float* wgs = wg + s * 1024;
  for (int d = 0; d < 1024; d += 4) {
#pragma unroll
    for (int u = 0; u < 4; ++u) {
      float4 w = *(const float4*)(Wlin + (d + u) * 4);
      float dot = lx * w.x + ly * w.y + ax * w.z + ay * w.w;
      dot = dot > 0.f ? dot : 0.f;
      float p = dot * wgs[d + u];
      if (u == 0) a0 += p; else if (u == 1) a1 += p; else if (u == 2) a2 += p; else a3 += p;
    }
  }
  float acc = (a0 + a1) + (a2 + a3);
  rp[s * 144 + t] = acc > 0.f ? acc : 0.f;
}

// ---------------- prep_all: rp + vt_pad + conv(weights) + conv(Q,K,V) in ONE launch ---
// All roles are 256-thread, no-LDS streaming blocks (identical occupancy profile).
//   [0,144) rp ; [144,656) vt pad ; [656,2192) conv weights ; [2192,29840) conv Q/K/V
__global__ void prep_all(const float* __restrict__ query, const float* __restrict__ key,
                         const float* __restrict__ value, _Float16* __restrict__ ia,
                         _Float16* __restrict__ ib, _Float16* __restrict__ ic,
                         const float* __restrict__ Wq, const float* __restrict__ Wk,
                         const float* __restrict__ Wv, _Float16* __restrict__ Wqb,
                         _Float16* __restrict__ Wkb, _Float16* __restrict__ Wvb,
                         const float* __restrict__ Wlin, const float* __restrict__ wg,
                         float* __restrict__ rp, _Float16* __restrict__ vt) {
  int id = blockIdx.x, t = threadIdx.x;
  if (id < 144) {
    rp_body(Wlin, wg, rp, id, t);
  } else if (id < 656) {
    int i = (id - 144) * 256 + t;                 // 131072 (b,e) rows
    _Float16* p = vt + (size_t)i * 160 + 144;
    *(half8*)p = (half8){};
    *(half8*)(p + 8) = (half8){};
  } else if (id < 2192) {
    int id3 = id - 656;
    int z = id3 >> 9, r = id3 & 511;              // 3 x 512 blocks, 2048 elems each
    const float* s = z == 0 ? Wq : (z == 1 ? Wk : Wv);
    _Float16* d = z == 0 ? Wqb : (z == 1 ? Wkb : Wvb);
    conv2048(s + r * 2048, d + r * 2048, t);
  } else {
    int id4 = id - 2192;
    int z = id4 / 9216, r = id4 % 9216;           // 3 x 9216 blocks, 2048 elems each
    const float* s = z == 0 ? query : (z == 1 ? key : value);
    _Float16* d = z == 0 ? ia : (z == 1 ? ib : ic);
    conv2048(s + (size_t)r * 2048, d + (size_t)r * 2048, t);
  }
}

// small-path prep (sequential layout): rp + vt_pad + conv weights only
__global__ void prep_small(const float* __restrict__ Wq, const float* __restrict__ Wk,
                           const float* __restrict__ Wv, _Float16* __restrict__ Wqb,
                           _Float16* __restrict__ Wkb, _Float16* __restrict__ Wvb,
                           const float* __restrict__ Wlin, const float* __restrict__ wg,
                           float* __restrict__ rp, _Float16* __restrict__ vt) {
  int id = blockIdx.x, t = threadIdx.x;
  if (id < 144) {
    rp_body(Wlin, wg, rp, id, t);
  } else if (id < 656) {
    int i = (id - 144) * 256 + t;
    _Float16* p = vt + (size_t)i * 160 + 144;
    *(half8*)p = (half8){};
    *(half8*)(p + 8) = (half8){};
  } else {
    int id3 = id - 656;
    int z = id3 >> 9, r = id3 & 511;
    const float* s = z == 0 ? Wq : (z == 1 ? Wk : Wv);
    _Float16* d = z == 0 ? Wqb : (z == 1 ? Wkb : Wvb);
    conv2048(s + r * 2048, d + r * 2048, t);
  }
}

// ---------------- f32 -> f16, 3 buffers in one launch (z selects; sequential path) ----
__global__ void conv3_f32_f16(const float* __restrict__ s0, const float* __restrict__ s1,
                              const float* __restrict__ s2, _Float16* __restrict__ d0,
                              _Float16* __restrict__ d1, _Float16* __restrict__ d2, int n) {
  const float* s = blockIdx.z == 0 ? s0 : (blockIdx.z == 1 ? s1 : s2);
  _Float16* d = blockIdx.z == 0 ? d0 : (blockIdx.z == 1 ? d1 : d2);
  int i = blockIdx.x * 2048;
  if (i >= n) return;
  conv2048(s + i, d + i, (int)threadIdx.x);
}

// ---------------- projection GEMM: C = relu(A * B^T + bias), f16 in/out ----------------
// 128(M)x128(N) block, 4 waves (2x2), wave-tile 64x64 (acc 4x4), BK=32.
// Same proven chunk machinery as R8 (16-row x 32-f16 = 1KB chunks, cg8 source rotation,
// rdoff fragment reads, 0 conflicts), triple-buffer depth-2, counted vmcnt(4)
// (4 loads/wave/slot; wait drains exactly the slot about to be consumed).
// 16KB slots x3 = 48KB LDS -> 3 blocks/CU (12 waves) to cover barrier drains.
// z == vtz writes the TRANSPOSED output into vt[(b*1024+e)*160+s] (replaces transpose_v).
__global__ __launch_bounds__(256, 2) void gemm_proj(
    const _Float16* __restrict__ a0q, const _Float16* __restrict__ a1q,
    const _Float16* __restrict__ a2q, const _Float16* __restrict__ w0q,
    const _Float16* __restrict__ w1q, const _Float16* __restrict__ w2q,
    const float* __restrict__ bi0, const float* __restrict__ bi1,
    const float* __restrict__ bi2, _Float16* __restrict__ c0q,
    _Float16* __restrict__ c1q, _Float16* __restrict__ c2q,
    _Float16* __restrict__ vtp, int vtz) {
  const _Float16* A = blockIdx.z == 0 ? a0q : (blockIdx.z == 1 ? a1q : a2q);
  const _Float16* W = blockIdx.z == 0 ? w0q : (blockIdx.z == 1 ? w1q : w2q);
  const float* bias = blockIdx.z == 0 ? bi0 : (blockIdx.z == 1 ? bi1 : bi2);
  _Float16* C = blockIdx.z == 0 ? c0q : (blockIdx.z == 1 ? c1q : c2q);

  __shared__ __align__(16) char lds[49152];  // 3 x 16KB slots (A 8KB + B 8KB each)
  int tid = threadIdx.x, wid = tid >> 6, lane = tid & 63;
  int lin = blockIdx.y * 8 + blockIdx.x;     // 0..1151 ; XCD-chunked, 144 per XCD
  int local = lin >> 3;
  int mt = (lin & 7) * 18 + (local >> 3), nt = local & 7;
  int m0 = mt * 128, n0 = nt * 128;

  int r4l = lane >> 2, c4 = lane & 3;
  int cg8 = ((c4 + (r4l >> 1)) & 3) * 8;                 // rotated source kslot (f16)
  int lr = lane & 15, lg = lane >> 4;
  int rdoff = lr * 64 + ((lg - (lr >> 1)) & 3) * 16;     // fragment read offset (bytes)

  // 16 chunks: 0..7 A rows m0+q*16, 8..15 B rows n0+(q-8)*16. Wave w stages c*4+w.
  const _Float16* gp[4];
#pragma unroll
  for (int c = 0; c < 4; ++c) {
    int q = c * 4 + wid;
    gp[c] = (q < 8) ? A + (size_t)(m0 + q * 16 + r4l) * 1024 + cg8
                    : W + (size_t)(n0 + (q - 8) * 16 + r4l) * 1024 + cg8;
  }
  char *sl0 = lds, *sl1 = lds + 16384, *sl2 = lds + 32768;
  auto issue = [&](char* slot) {
#pragma unroll
    for (int c = 0; c < 4; ++c) { gload_lds16(gp[c], slot + (c * 4 + wid) * 1024); gp[c] += 32; }
  };
  issue(sl0);
  issue(sl1);
  f32x4 acc[4][4] = {};
  int abase = (wid >> 1) * 4096, bbase = 8192 + (wid & 1) * 4096;
  for (int t = 0; t < 32; ++t) {
    asm volatile("s_waitcnt vmcnt(4)" ::: "memory");
    __builtin_amdgcn_s_barrier();
    __builtin_amdgcn_sched_barrier(0);
    issue(sl2);  // unconditional; tail prefetch reads in-bounds garbage (ws interior)
    half8 a[4], b[4];
#pragma unroll
    for (int i = 0; i < 4; ++i) a[i] = *(const half8*)(sl0 + abase + i * 1024 + rdoff);
#pragma unroll
    for (int j = 0; j < 4; ++j) b[j] = *(const half8*)(sl0 + bbase + j * 1024 + rdoff);
#pragma unroll
    for (int i = 0; i < 4; ++i)
#pragma unroll
      for (int j = 0; j < 4; ++j)
        acc[i][j] = mfma16x32(b[j], a[i], acc[i][j]);  // swapped: lane holds 4 consec cols
    char* tmp = sl0; sl0 = sl1; sl1 = sl2; sl2 = tmp;
  }
  // epilogue: bias + relu -> f16. Normal z: 8B vector stores to C.
  // z == vtz: transposed scatter into vt (16-consecutive-s x 2B = 32B segments).
  int wm = (wid >> 1) * 64, wn = (wid & 1) * 64;
  bool tov = (vtp != nullptr) && ((int)blockIdx.z == vtz);
#pragma unroll
  for (int i = 0; i < 4; ++i) {
    int row = m0 + wm + i * 16 + lr;
#pragma unroll
    for (int j = 0; j < 4; ++j) {
      int col = n0 + wn + j * 16 + lg * 4;
      float4 b4 = *(const float4*)(bias + col);
      half4 h;
      float v0 = acc[i][j][0] + b4.x; h[0] = (_Float16)(v0 > 0.f ? v0 : 0.f);
      float v1 = acc[i][j][1] + b4.y; h[1] = (_Float16)(v1 > 0.f ? v1 : 0.f);
      float v2 = acc[i][j][2] + b4.z; h[2] = (_Float16)(v2 > 0.f ? v2 : 0.f);
      float v3 = acc[i][j][3] + b4.w; h[3] = (_Float16)(v3 > 0.f ? v3 : 0.f);
      if (tov) {
        int bb = row / 144, ss = row - bb * 144;
        _Float16* vb = vtp + (size_t)(bb * 1024 + col) * 160 + ss;
        vb[0] = h[0]; vb[160] = h[1]; vb[320] = h[2]; vb[480] = h[3];
      } else {
        *(half4*)(C + (size_t)row * 1024 + col) = h;
      }
    }
  }
}

// ---------------- fused attention per (batch, 48-row third) ----------------  (R3-exact)
// q,k [18432][1024] f16 ; vt [b*1024+e][160] f16 (pad cols finite) ; rp [144][144] f32
__global__ __launch_bounds__(256) void attn_kernel(const _Float16* __restrict__ q,
                                                   const _Float16* __restrict__ k,
                                                   const _Float16* __restrict__ vt,
                                                   const float* __restrict__ rp,
                                                   float* __restrict__ out) {
  __shared__ __align__(16) char lds[53248];
  // phase1 slots: 0 / 12288 / 24576 (12KB) ; phase2 slots: 0 / 16384 (16KB)
  // sc (f32, stride 152) aliases 0..29184 ; P @36864 (48x168 f16) ; sums @52992
  float* sc = (float*)lds;
  _Float16* P = (_Float16*)(lds + 36864);
  float* sums = (float*)(lds + 52992);

  int tid = threadIdx.x, wid = tid >> 6, lane = tid & 63;
  int lin = blockIdx.y * 3 + blockIdx.x;       // 0..383
  int swz = (lin & 7) * 48 + (lin >> 3);
  int mt3 = swz % 3, b = swz / 3;
  int m0 = mt3 * 48;
  const int nstart_t[4] = {0, 3, 5, 7};
  const int ncnt_t[4]   = {3, 2, 2, 2};
  int ns = nstart_t[wid], nc = ncnt_t[wid];
  int r4l = lane >> 2, c4 = lane & 3;
  int cg8 = ((c4 + (r4l >> 1)) & 3) * 8;
  int lr = lane & 15, lg = lane >> 4;
  int rdoff = lr * 64 + ((lg - (lr >> 1)) & 3) * 16;   // bytes

  // ---- phase 1: scores = q . k^T over K=1024, triple-buffer depth-2 ----
  {
    char *sl0 = lds, *sl1 = lds + 12288, *sl2 = lds + 24576;
    const _Float16* g1[3];
#pragma unroll
    for (int c = 0; c < 3; ++c) {
      int qq = c * 4 + wid;  // 0..2 -> q chunks (48 rows), 3..11 -> k chunks (144 rows)
      g1[c] = (qq < 3) ? q + (size_t)(b * 144 + m0 + qq * 16 + r4l) * 1024 + cg8
                       : k + (size_t)(b * 144 + (qq - 3) * 16 + r4l) * 1024 + cg8;
    }
    auto issue1 = [&](char* slot) {
#pragma unroll
      for (int c = 0; c < 3; ++c) {
        gload_lds16(g1[c], slot + (c * 4 + wid) * 1024);
        g1[c] += 32;
      }
    };
    issue1(sl0);
    issue1(sl1);
    f32x4 acc[3][3] = {};
    for (int t = 0; t < 32; ++t) {
      asm volatile("s_waitcnt vmcnt(3)" ::: "memory");
      __builtin_amdgcn_sched_barrier(0);
      __builtin_amdgcn_s_barrier();
      __builtin_amdgcn_sched_barrier(0);
      issue1(sl2);  // tail garbage stays inside readable ws
      half8 af[3], bf[3];
#pragma unroll
      for (int i = 0; i < 3; ++i)
        af[i] = *(const half8*)(sl0 + i * 1024 + rdoff);
#pragma unroll
      for (int j = 0; j < 3; ++j)
        if (j < nc)
          bf[j] = *(const half8*)(sl0 + (3 + ns + j) * 1024 + rdoff);
#pragma unroll
      for (int i = 0; i < 3; ++i)
#pragma unroll
        for (int j = 0; j < 3; ++j)
          if (j < nc)
            acc[i][j] = mfma16x32(bf[j], af[i], acc[i][j]);  // swapped
      char* tmp = sl0; sl0 = sl1; sl1 = sl2; sl2 = tmp;
    }
    asm volatile("s_waitcnt vmcnt(0)" ::: "memory");
    __syncthreads();  // straggler prefetches drained before sc aliases the slots
    const float scale = 0.03125f;  // 1024^-0.5
#pragma unroll
    for (int i = 0; i < 3; ++i) {
      int qrow = i * 16 + lr;
#pragma unroll
      for (int j = 0; j < 3; ++j)
        if (j < nc) {
          int kc0 = (ns + j) * 16 + lg * 4;
          float4 rr = *(const float4*)(rp + (m0 + qrow) * 144 + kc0);
          f32x4 vs;
          vs[0] = acc[i][j][0] * scale + rr.x;
          vs[1] = acc[i][j][1] * scale + rr.y;
          vs[2] = acc[i][j][2] * scale + rr.z;
          vs[3] = acc[i][j][3] * scale + rr.w;
          *(f32x4*)(sc + qrow * 152 + kc0) = vs;
        }
    }
  }
  __syncthreads();

  // ---- softmax (unnormalized; sums kept for epilogue) ----
  if (tid < 192) {
    int r = tid >> 2, qd = tid & 3;
    int cb = qd * 36;
    float m = -1e30f;
    for (int c2 = 0; c2 < 36; ++c2) m = fmaxf(m, sc[r * 152 + cb + c2]);
    m = fmaxf(m, __shfl_xor(m, 1));
    m = fmaxf(m, __shfl_xor(m, 2));
    float s = 0.f;
    for (int c2 = 0; c2 < 36; ++c2) {
      float e = __expf(sc[r * 152 + cb + c2] - m);
      s += e;
      P[r * 168 + cb + c2] = (_Float16)e;
    }
    s += __shfl_xor(s, 1);
    s += __shfl_xor(s, 2);
    if (qd == 0) sums[r] = s;
  }
  if (tid < 96) {  // zero-pad P cols 144..159
    int r = tid >> 1, c0 = 144 + (tid & 1) * 8;
    *(half8*)(P + r * 168 + c0) = (half8){};
  }
  __syncthreads();

  // ---- phase 2: out = (P @ V) / sums — 20 uniform K=32 iters, 2 slots depth-1 ----
  char *s0p = lds, *s1p = lds + 16384;
  auto issue2 = [&](int idx, char* slot) {
    int nn0 = (idx / 5) * 256, kk0 = (idx % 5) * 32;
#pragma unroll
    for (int c = 0; c < 4; ++c) {
      int ch = c * 4 + wid;  // 16 chunks of 16 rows
      gload_lds16(vt + (size_t)(b * 1024 + nn0 + ch * 16 + r4l) * 160 + kk0 + cg8,
                  slot + ch * 1024);
    }
  };
  issue2(0, s0p);
  f32x4 o[3][4] = {};
  for (int it = 0; it < 20; ++it) {
    asm volatile("s_waitcnt vmcnt(0)" ::: "memory");
    __builtin_amdgcn_sched_barrier(0);
    __builtin_amdgcn_s_barrier();
    __builtin_amdgcn_sched_barrier(0);
    issue2(it + 1, ((it + 1) & 1) ? s1p : s0p);  // it=19 -> garbage into region after vt
    char* sb = (it & 1) ? s1p : s0p;
    int k0 = (it % 5) * 32;
    half8 af[3], bf[4];
#pragma unroll
    for (int i = 0; i < 3; ++i)
      af[i] = *(const half8*)(P + (i * 16 + lr) * 168 + k0 + lg * 8);
#pragma unroll
    for (int j = 0; j < 4; ++j)
      bf[j] = *(const half8*)(sb + (wid * 4 + j) * 1024 + rdoff);
#pragma unroll
    for (int i = 0; i < 3; ++i)
#pragma unroll
      for (int j = 0; j < 4; ++j)
        o[i][j] = mfma16x32(bf[j], af[i], o[i][j]);  // swapped
    if (it % 5 == 4) {
      int n0 = (it / 5) * 256;
#pragma unroll
      for (int i = 0; i < 3; ++i) {
        int row = i * 16 + lr;
        float inv = 1.f / sums[row];
#pragma unroll
        for (int j = 0; j < 4; ++j) {
          f32x4 vo;
          vo[0] = o[i][j][0] * inv; vo[1] = o[i][j][1] * inv;
          vo[2] = o[i][j][2] * inv; vo[3] = o[i][j][3] * inv;
          *(f32x4*)(out + (size_t)(b * 144 + m0 + row) * 1024 + n0 + wid * 64 + j * 16 + lg * 4) = vo;
          o[i][j] = (f32x4){};
        }
      }
    }
  }
}

extern "C" void kernel_launch(void* const* d_in, const int* in_sizes, int n_in,
                              void* d_out, int out_size, void* d_ws, size_t ws_size,
                              hipStream_t stream) {
  const float* query = (const float*)d_in[0];
  const float* key   = (const float*)d_in[1];
  const float* value = (const float*)d_in[2];
  const float* Wq    = (const float*)d_in[3];
  const float* bq    = (const float*)d_in[4];
  const float* Wk    = (const float*)d_in[5];
  const float* bk    = (const float*)d_in[6];
  const float* Wv    = (const float*)d_in[7];
  const float* bv    = (const float*)d_in[8];
  const float* Wlin  = (const float*)d_in[9];
  const float* wg    = (const float*)d_in[10];
  float* out = (float*)d_out;

  char* ws = (char*)d_ws;
  const size_t NQKV = (size_t)18432 * 1024;            // 37.75 MB as f16
  const size_t NVT  = (size_t)131072 * 160;            // padded vt (40 MB)
  // layout: [W 6MB][rp 128KB][qp][kp][vt 40MB][...path-specific]  (R3-proven)
  _Float16* Wqb = (_Float16*)(ws);
  _Float16* Wkb = (_Float16*)(ws + (2u << 20));
  _Float16* Wvb = (_Float16*)(ws + (4u << 20));
  float*    rp  = (float*)(ws + (6u << 20));
  _Float16* qp  = (_Float16*)(ws + (6u << 20) + 131072);
  _Float16* kp  = qp + NQKV;
  _Float16* vt  = kp + NQKV;                           // 40MB; written by gemm z==vtz

  dim3 agrid(3, 128);

  if (ws_size >= 238000000ull) {
    // parallel layout: all three f16 inputs live at once; ONE prep launch, one z=3 GEMM.
    _Float16* ia = vt + NVT + 32768;   // 64KB guard (attn tail prefetch overrun lands here)
    _Float16* ib = ia + NQKV;
    _Float16* ic = ib + NQKV;
    prep_all<<<29840, 256, 0, stream>>>(query, key, value, ia, ib, ic,
                                        Wq, Wk, Wv, Wqb, Wkb, Wvb,
                                        Wlin, wg, rp, vt);
    gemm_proj<<<dim3(8, 144, 3), 256, 0, stream>>>(ia, ib, ic, Wqb, Wkb, Wvb,
                                                   bq, bk, bv, qp, kp, kp /*unused z2*/,
                                                   vt, 2);
    attn_kernel<<<agrid, 256, 0, stream>>>(qp, kp, vt, rp, out);
  } else {
    // sequential layout: shared input buffer after vt.
    _Float16* inb = vt + NVT;          // also absorbs attn tail-prefetch overrun
    prep_small<<<2192, 256, 0, stream>>>(Wq, Wk, Wv, Wqb, Wkb, Wvb, Wlin, wg, rp, vt);
    conv3_f32_f16<<<dim3((int)(NQKV / 2048), 1, 1), 256, 0, stream>>>(
        query, query, query, inb, inb, inb, (int)NQKV);
    gemm_proj<<<dim3(8, 144, 1), 256, 0, stream>>>(inb, inb, inb, Wqb, Wqb, Wqb,
                                                   bq, bq, bq, qp, qp, qp, nullptr, -1);
    conv3_f32_f16<<<dim3((int)(NQKV / 2048), 1, 1), 256, 0, stream>>>(
        key, key, key, inb, inb, inb, (int)NQKV);
    gemm_proj<<<dim3(8, 144, 1), 256, 0, stream>>>(inb, inb, inb, Wkb, Wkb, Wkb,
                                                   bk, bk, bk, kp, kp, kp, nullptr, -1);
    conv3_f32_f16<<<dim3((int)(NQKV / 2048), 1, 1), 256, 0, stream>>>(
        value, value, value, inb, inb, inb, (int)NQKV);
    gemm_proj<<<dim3(8, 144, 1), 256, 0, stream>>>(inb, inb, inb, Wvb, Wvb, Wvb,
                                                   bv, bv, bv, qp /*unused*/, qp, qp,
                                                   vt, 0);
    attn_kernel<<<agrid, 256, 0, stream>>>(qp, kp, vt, rp, out);
  }
}

// Round 10
// 277.299 us; speedup vs baseline: 1.0729x; 1.0729x over previous
//
#include <hip/hip_runtime.h>
#include <hip/hip_fp16.h>

#define DEV __device__ __forceinline__

using half8 = __attribute__((ext_vector_type(8))) _Float16;
using half4 = __attribute__((ext_vector_type(4))) _Float16;
using f32x4 = __attribute__((ext_vector_type(4))) float;

// async global->LDS, 16B per lane. LDS dest is wave-uniform base + lane*16B.
DEV void gload_lds16(const void* g, void* l) {
  __builtin_amdgcn_global_load_lds((const __attribute__((address_space(1))) unsigned int*)g,
                                   (__attribute__((address_space(3))) unsigned int*)l,
                                   16, 0, 0);
}

DEV f32x4 mfma16x32(half8 a, half8 b, f32x4 c) {
  return __builtin_amdgcn_mfma_f32_16x16x32_f16(a, b, c, 0, 0, 0);
}

DEV void conv2048(const float* __restrict__ s, _Float16* __restrict__ d, int t) {
  int i = t * 8;
  float4 a = *(const float4*)(s + i);
  float4 b = *(const float4*)(s + i + 4);
  half8 h;
  h[0] = (_Float16)a.x; h[1] = (_Float16)a.y; h[2] = (_Float16)a.z; h[3] = (_Float16)a.w;
  h[4] = (_Float16)b.x; h[5] = (_Float16)b.y; h[6] = (_Float16)b.z; h[7] = (_Float16)b.w;
  *(half8*)(d + i) = h;
}

DEV void rp_body(const float* __restrict__ Wlin, const float* __restrict__ wg,
                 float* __restrict__ rp, int s, int t) {
  if (t >= 144) return;
  int rs = s / 12, cs = s % 12, rt = t / 12, ct = t % 12;
  float dx = (cs - ct) / 12.f, dy = (rs - rt) / 12.f;
  float ax = (dx > 0.f) ? 0.5f : (dx < 0.f ? -0.5f : 0.f);
  float ay = (dy > 0.f) ? 0.5f : (dy < 0.f ? -0.5f : 0.f);
  float lx = fabsf(logf(fabsf(dx) + 0.5f));
  float ly = fabsf(logf(fabsf(dy) + 0.5f));
  float a0 = 0.f, a1 = 0.f, a2 = 0.f, a3 = 0.f;
  const float* wgs = wg + s * 1024;
  for (int d = 0; d < 1024; d += 4) {
#pragma unroll
    for (int u = 0; u < 4; ++u) {
      float4 w = *(const float4*)(Wlin + (d + u) * 4);
      float dot = lx * w.x + ly * w.y + ax * w.z + ay * w.w;
      dot = dot > 0.f ? dot : 0.f;
      float p = dot * wgs[d + u];
      if (u == 0) a0 += p; else if (u == 1) a1 += p; else if (u == 2) a2 += p; else a3 += p;
    }
  }
  float acc = (a0 + a1) + (a2 + a3);
  rp[s * 144 + t] = acc > 0.f ? acc : 0.f;
}

// ---------------- prep_all: rp + vt_pad + conv(weights) + conv(Q,K,V) in ONE launch ---
// All roles are 256-thread, no-LDS streaming blocks (identical occupancy profile).
//   [0,144) rp ; [144,656) vt pad ; [656,2192) conv weights ; [2192,29840) conv Q/K/V
__global__ void prep_all(const float* __restrict__ query, const float* __restrict__ key,
                         const float* __restrict__ value, _Float16* __restrict__ ia,
                         _Float16* __restrict__ ib, _Float16* __restrict__ ic,
                         const float* __restrict__ Wq, const float* __restrict__ Wk,
                         const float* __restrict__ Wv, _Float16* __restrict__ Wqb,
                         _Float16* __restrict__ Wkb, _Float16* __restrict__ Wvb,
                         const float* __restrict__ Wlin, const float* __restrict__ wg,
                         float* __restrict__ rp, _Float16* __restrict__ vt) {
  int id = blockIdx.x, t = threadIdx.x;
  if (id < 144) {
    rp_body(Wlin, wg, rp, id, t);
  } else if (id < 656) {
    int i = (id - 144) * 256 + t;                 // 131072 (b,e) rows
    _Float16* p = vt + (size_t)i * 160 + 144;
    *(half8*)p = (half8){};
    *(half8*)(p + 8) = (half8){};
  } else if (id < 2192) {
    int id3 = id - 656;
    int z = id3 >> 9, r = id3 & 511;              // 3 x 512 blocks, 2048 elems each
    const float* s = z == 0 ? Wq : (z == 1 ? Wk : Wv);
    _Float16* d = z == 0 ? Wqb : (z == 1 ? Wkb : Wvb);
    conv2048(s + r * 2048, d + r * 2048, t);
  } else {
    int id4 = id - 2192;
    int z = id4 / 9216, r = id4 % 9216;           // 3 x 9216 blocks, 2048 elems each
    const float* s = z == 0 ? query : (z == 1 ? key : value);
    _Float16* d = z == 0 ? ia : (z == 1 ? ib : ic);
    conv2048(s + (size_t)r * 2048, d + (size_t)r * 2048, t);
  }
}

// small-path prep (sequential layout): rp + vt_pad + conv weights only
__global__ void prep_small(const float* __restrict__ Wq, const float* __restrict__ Wk,
                           const float* __restrict__ Wv, _Float16* __restrict__ Wqb,
                           _Float16* __restrict__ Wkb, _Float16* __restrict__ Wvb,
                           const float* __restrict__ Wlin, const float* __restrict__ wg,
                           float* __restrict__ rp, _Float16* __restrict__ vt) {
  int id = blockIdx.x, t = threadIdx.x;
  if (id < 144) {
    rp_body(Wlin, wg, rp, id, t);
  } else if (id < 656) {
    int i = (id - 144) * 256 + t;
    _Float16* p = vt + (size_t)i * 160 + 144;
    *(half8*)p = (half8){};
    *(half8*)(p + 8) = (half8){};
  } else {
    int id3 = id - 656;
    int z = id3 >> 9, r = id3 & 511;
    const float* s = z == 0 ? Wq : (z == 1 ? Wk : Wv);
    _Float16* d = z == 0 ? Wqb : (z == 1 ? Wkb : Wvb);
    conv2048(s + r * 2048, d + r * 2048, t);
  }
}

// ---------------- f32 -> f16, 3 buffers in one launch (z selects; sequential path) ----
__global__ void conv3_f32_f16(const float* __restrict__ s0, const float* __restrict__ s1,
                              const float* __restrict__ s2, _Float16* __restrict__ d0,
                              _Float16* __restrict__ d1, _Float16* __restrict__ d2, int n) {
  const float* s = blockIdx.z == 0 ? s0 : (blockIdx.z == 1 ? s1 : s2);
  _Float16* d = blockIdx.z == 0 ? d0 : (blockIdx.z == 1 ? d1 : d2);
  int i = blockIdx.x * 2048;
  if (i >= n) return;
  conv2048(s + i, d + i, (int)threadIdx.x);
}

// ---------------- projection GEMM: C = relu(A * B^T + bias), f16 in/out ----------------
// 288(M)x128(N) block, 4 waves (2x2), wave-tile 144x64 (acc 9x4), BK=32.
// Same proven chunk machinery as R8 (16-row x 32-f16 = 1KB chunks, cg8 source rotation,
// rdoff fragment reads, 0 conflicts), triple-buffer depth-2, counted per-wave vmcnt.
// 26 chunks/slot (A 18 + B 8): waves 0,1 stage 7 chunks, waves 2,3 stage 6 ->
// vmcnt(7)/vmcnt(6) respectively (per-wave FIFO: prologue 14/12 outstanding; wait
// retires exactly the slot about to be consumed). 26KB slots x3 = 78KB -> 2 blocks/CU.
// 288 tile => per-z grid 512 blocks, total 1536 = EXACTLY 3 rounds of 512 resident
// (R8's 1728 = 3.375 rounds had a 37%-occupancy tail round).
// z == vtz writes the TRANSPOSED output into vt[(b*1024+e)*160+s] (replaces transpose_v).
__global__ __launch_bounds__(256, 2) void gemm_proj(
    const _Float16* __restrict__ a0q, const _Float16* __restrict__ a1q,
    const _Float16* __restrict__ a2q, const _Float16* __restrict__ w0q,
    const _Float16* __restrict__ w1q, const _Float16* __restrict__ w2q,
    const float* __restrict__ bi0, const float* __restrict__ bi1,
    const float* __restrict__ bi2, _Float16* __restrict__ c0q,
    _Float16* __restrict__ c1q, _Float16* __restrict__ c2q,
    _Float16* __restrict__ vtp, int vtz) {
  const _Float16* A = blockIdx.z == 0 ? a0q : (blockIdx.z == 1 ? a1q : a2q);
  const _Float16* W = blockIdx.z == 0 ? w0q : (blockIdx.z == 1 ? w1q : w2q);
  const float* bias = blockIdx.z == 0 ? bi0 : (blockIdx.z == 1 ? bi1 : bi2);
  _Float16* C = blockIdx.z == 0 ? c0q : (blockIdx.z == 1 ? c1q : c2q);

  __shared__ __align__(16) char lds[79872];  // 3 x 26KB slots (A 18KB + B 8KB each)
  int tid = threadIdx.x, wid = tid >> 6, lane = tid & 63;
  int lin = blockIdx.y * 8 + blockIdx.x;     // 0..511 per z ; XCD-chunked, 64 per XCD
  int local = lin >> 3;                      // 0..63
  int mt = (lin & 7) * 8 + (local >> 3), nt = local & 7;   // mt 0..63, nt 0..7
  int m0 = mt * 288, n0 = nt * 128;

  int r4l = lane >> 2, c4 = lane & 3;
  int cg8 = ((c4 + (r4l >> 1)) & 3) * 8;                 // rotated source kslot (f16)
  int lr = lane & 15, lg = lane >> 4;
  int rdoff = lr * 64 + ((lg - (lr >> 1)) & 3) * 16;     // fragment read offset (bytes)

  // 26 chunks: 0..17 A rows m0+q*16, 18..25 B rows n0+(q-18)*16. Wave w stages c*4+w.
  const _Float16* gp[7];
  int nch = (wid < 2) ? 7 : 6;
#pragma unroll
  for (int c = 0; c < 7; ++c) {
    int q = c * 4 + wid;
    if (q < 26)
      gp[c] = (q < 18) ? A + (size_t)(m0 + q * 16 + r4l) * 1024 + cg8
                       : W + (size_t)(n0 + (q - 18) * 16 + r4l) * 1024 + cg8;
    else
      gp[c] = A;  // unused
  }
  char *sl0 = lds, *sl1 = lds + 26624, *sl2 = lds + 53248;
  auto issue = [&](char* slot) {
#pragma unroll
    for (int c = 0; c < 7; ++c) {
      if (c * 4 + wid < 26) { gload_lds16(gp[c], slot + (c * 4 + wid) * 1024); gp[c] += 32; }
    }
  };
  issue(sl0);
  issue(sl1);
  f32x4 acc[9][4] = {};
  int abase = (wid >> 1) * 9216, bbase = 18432 + (wid & 1) * 4096;
  for (int t = 0; t < 32; ++t) {
    // per-wave counted vmcnt: retires exactly the slot consumed this iteration
    if (wid < 2) asm volatile("s_waitcnt vmcnt(7)" ::: "memory");
    else         asm volatile("s_waitcnt vmcnt(6)" ::: "memory");
    __builtin_amdgcn_s_barrier();
    __builtin_amdgcn_sched_barrier(0);
    issue(sl2);  // unconditional; tail prefetch reads in-bounds garbage (ws interior)
    half8 a[9], b[4];
#pragma unroll
    for (int i = 0; i < 9; ++i) a[i] = *(const half8*)(sl0 + abase + i * 1024 + rdoff);
#pragma unroll
    for (int j = 0; j < 4; ++j) b[j] = *(const half8*)(sl0 + bbase + j * 1024 + rdoff);
#pragma unroll
    for (int i = 0; i < 9; ++i)
#pragma unroll
      for (int j = 0; j < 4; ++j)
        acc[i][j] = mfma16x32(b[j], a[i], acc[i][j]);  // swapped: lane holds 4 consec cols
    char* tmp = sl0; sl0 = sl1; sl1 = sl2; sl2 = tmp;
  }
  // epilogue: bias + relu -> f16. Normal z: 8B vector stores to C.
  // z == vtz: transposed scatter into vt (16-consecutive-s x 2B = 32B segments).
  int wm = (wid >> 1) * 144, wn = (wid & 1) * 64;
  bool tov = (vtp != nullptr) && ((int)blockIdx.z == vtz);
#pragma unroll
  for (int i = 0; i < 9; ++i) {
    int row = m0 + wm + i * 16 + lr;
#pragma unroll
    for (int j = 0; j < 4; ++j) {
      int col = n0 + wn + j * 16 + lg * 4;
      float4 b4 = *(const float4*)(bias + col);
      half4 h;
      float v0 = acc[i][j][0] + b4.x; h[0] = (_Float16)(v0 > 0.f ? v0 : 0.f);
      float v1 = acc[i][j][1] + b4.y; h[1] = (_Float16)(v1 > 0.f ? v1 : 0.f);
      float v2 = acc[i][j][2] + b4.z; h[2] = (_Float16)(v2 > 0.f ? v2 : 0.f);
      float v3 = acc[i][j][3] + b4.w; h[3] = (_Float16)(v3 > 0.f ? v3 : 0.f);
      if (tov) {
        int bb = row / 144, ss = row - bb * 144;
        _Float16* vb = vtp + (size_t)(bb * 1024 + col) * 160 + ss;
        vb[0] = h[0]; vb[160] = h[1]; vb[320] = h[2]; vb[480] = h[3];
      } else {
        *(half4*)(C + (size_t)row * 1024 + col) = h;
      }
    }
  }
}

// ---------------- fused attention per (batch, 48-row third) ----------------  (R3-exact)
// q,k [18432][1024] f16 ; vt [b*1024+e][160] f16 (pad cols finite) ; rp [144][144] f32
__global__ __launch_bounds__(256) void attn_kernel(const _Float16* __restrict__ q,
                                                   const _Float16* __restrict__ k,
                                                   const _Float16* __restrict__ vt,
                                                   const float* __restrict__ rp,
                                                   float* __restrict__ out) {
  __shared__ __align__(16) char lds[53248];
  // phase1 slots: 0 / 12288 / 24576 (12KB) ; phase2 slots: 0 / 16384 (16KB)
  // sc (f32, stride 152) aliases 0..29184 ; P @36864 (48x168 f16) ; sums @52992
  float* sc = (float*)lds;
  _Float16* P = (_Float16*)(lds + 36864);
  float* sums = (float*)(lds + 52992);

  int tid = threadIdx.x, wid = tid >> 6, lane = tid & 63;
  int lin = blockIdx.y * 3 + blockIdx.x;       // 0..383
  int swz = (lin & 7) * 48 + (lin >> 3);
  int mt3 = swz % 3, b = swz / 3;
  int m0 = mt3 * 48;
  const int nstart_t[4] = {0, 3, 5, 7};
  const int ncnt_t[4]   = {3, 2, 2, 2};
  int ns = nstart_t[wid], nc = ncnt_t[wid];
  int r4l = lane >> 2, c4 = lane & 3;
  int cg8 = ((c4 + (r4l >> 1)) & 3) * 8;
  int lr = lane & 15, lg = lane >> 4;
  int rdoff = lr * 64 + ((lg - (lr >> 1)) & 3) * 16;   // bytes

  // ---- phase 1: scores = q . k^T over K=1024, triple-buffer depth-2 ----
  {
    char *sl0 = lds, *sl1 = lds + 12288, *sl2 = lds + 24576;
    const _Float16* g1[3];
#pragma unroll
    for (int c = 0; c < 3; ++c) {
      int qq = c * 4 + wid;  // 0..2 -> q chunks (48 rows), 3..11 -> k chunks (144 rows)
      g1[c] = (qq < 3) ? q + (size_t)(b * 144 + m0 + qq * 16 + r4l) * 1024 + cg8
                       : k + (size_t)(b * 144 + (qq - 3) * 16 + r4l) * 1024 + cg8;
    }
    auto issue1 = [&](char* slot) {
#pragma unroll
      for (int c = 0; c < 3; ++c) {
        gload_lds16(g1[c], slot + (c * 4 + wid) * 1024);
        g1[c] += 32;
      }
    };
    issue1(sl0);
    issue1(sl1);
    f32x4 acc[3][3] = {};
    for (int t = 0; t < 32; ++t) {
      asm volatile("s_waitcnt vmcnt(3)" ::: "memory");
      __builtin_amdgcn_sched_barrier(0);
      __builtin_amdgcn_s_barrier();
      __builtin_amdgcn_sched_barrier(0);
      issue1(sl2);  // tail garbage stays inside readable ws
      half8 af[3], bf[3];
#pragma unroll
      for (int i = 0; i < 3; ++i)
        af[i] = *(const half8*)(sl0 + i * 1024 + rdoff);
#pragma unroll
      for (int j = 0; j < 3; ++j)
        if (j < nc)
          bf[j] = *(const half8*)(sl0 + (3 + ns + j) * 1024 + rdoff);
#pragma unroll
      for (int i = 0; i < 3; ++i)
#pragma unroll
        for (int j = 0; j < 3; ++j)
          if (j < nc)
            acc[i][j] = mfma16x32(bf[j], af[i], acc[i][j]);  // swapped
      char* tmp = sl0; sl0 = sl1; sl1 = sl2; sl2 = tmp;
    }
    asm volatile("s_waitcnt vmcnt(0)" ::: "memory");
    __syncthreads();  // straggler prefetches drained before sc aliases the slots
    const float scale = 0.03125f;  // 1024^-0.5
#pragma unroll
    for (int i = 0; i < 3; ++i) {
      int qrow = i * 16 + lr;
#pragma unroll
      for (int j = 0; j < 3; ++j)
        if (j < nc) {
          int kc0 = (ns + j) * 16 + lg * 4;
          float4 rr = *(const float4*)(rp + (m0 + qrow) * 144 + kc0);
          f32x4 vs;
          vs[0] = acc[i][j][0] * scale + rr.x;
          vs[1] = acc[i][j][1] * scale + rr.y;
          vs[2] = acc[i][j][2] * scale + rr.z;
          vs[3] = acc[i][j][3] * scale + rr.w;
          *(f32x4*)(sc + qrow * 152 + kc0) = vs;
        }
    }
  }
  __syncthreads();

  // ---- softmax (unnormalized; sums kept for epilogue) ----
  if (tid < 192) {
    int r = tid >> 2, qd = tid & 3;
    int cb = qd * 36;
    float m = -1e30f;
    for (int c2 = 0; c2 < 36; ++c2) m = fmaxf(m, sc[r * 152 + cb + c2]);
    m = fmaxf(m, __shfl_xor(m, 1));
    m = fmaxf(m, __shfl_xor(m, 2));
    float s = 0.f;
    for (int c2 = 0; c2 < 36; ++c2) {
      float e = __expf(sc[r * 152 + cb + c2] - m);
      s += e;
      P[r * 168 + cb + c2] = (_Float16)e;
    }
    s += __shfl_xor(s, 1);
    s += __shfl_xor(s, 2);
    if (qd == 0) sums[r] = s;
  }
  if (tid < 96) {  // zero-pad P cols 144..159
    int r = tid >> 1, c0 = 144 + (tid & 1) * 8;
    *(half8*)(P + r * 168 + c0) = (half8){};
  }
  __syncthreads();

  // ---- phase 2: out = (P @ V) / sums — 20 uniform K=32 iters, 2 slots depth-1 ----
  char *s0p = lds, *s1p = lds + 16384;
  auto issue2 = [&](int idx, char* slot) {
    int nn0 = (idx / 5) * 256, kk0 = (idx % 5) * 32;
#pragma unroll
    for (int c = 0; c < 4; ++c) {
      int ch = c * 4 + wid;  // 16 chunks of 16 rows
      gload_lds16(vt + (size_t)(b * 1024 + nn0 + ch * 16 + r4l) * 160 + kk0 + cg8,
                  slot + ch * 1024);
    }
  };
  issue2(0, s0p);
  f32x4 o[3][4] = {};
  for (int it = 0; it < 20; ++it) {
    asm volatile("s_waitcnt vmcnt(0)" ::: "memory");
    __builtin_amdgcn_sched_barrier(0);
    __builtin_amdgcn_s_barrier();
    __builtin_amdgcn_sched_barrier(0);
    issue2(it + 1, ((it + 1) & 1) ? s1p : s0p);  // it=19 -> garbage into region after vt
    char* sb = (it & 1) ? s1p : s0p;
    int k0 = (it % 5) * 32;
    half8 af[3], bf[4];
#pragma unroll
    for (int i = 0; i < 3; ++i)
      af[i] = *(const half8*)(P + (i * 16 + lr) * 168 + k0 + lg * 8);
#pragma unroll
    for (int j = 0; j < 4; ++j)
      bf[j] = *(const half8*)(sb + (wid * 4 + j) * 1024 + rdoff);
#pragma unroll
    for (int i = 0; i < 3; ++i)
#pragma unroll
      for (int j = 0; j < 4; ++j)
        o[i][j] = mfma16x32(bf[j], af[i], o[i][j]);  // swapped
    if (it % 5 == 4) {
      int n0 = (it / 5) * 256;
#pragma unroll
      for (int i = 0; i < 3; ++i) {
        int row = i * 16 + lr;
        float inv = 1.f / sums[row];
#pragma unroll
        for (int j = 0; j < 4; ++j) {
          f32x4 vo;
          vo[0] = o[i][j][0] * inv; vo[1] = o[i][j][1] * inv;
          vo[2] = o[i][j][2] * inv; vo[3] = o[i][j][3] * inv;
          *(f32x4*)(out + (size_t)(b * 144 + m0 + row) * 1024 + n0 + wid * 64 + j * 16 + lg * 4) = vo;
          o[i][j] = (f32x4){};
        }
      }
    }
  }
}

extern "C" void kernel_launch(void* const* d_in, const int* in_sizes, int n_in,
                              void* d_out, int out_size, void* d_ws, size_t ws_size,
                              hipStream_t stream) {
  const float* query = (const float*)d_in[0];
  const float* key   = (const float*)d_in[1];
  const float* value = (const float*)d_in[2];
  const float* Wq    = (const float*)d_in[3];
  const float* bq    = (const float*)d_in[4];
  const float* Wk    = (const float*)d_in[5];
  const float* bk    = (const float*)d_in[6];
  const float* Wv    = (const float*)d_in[7];
  const float* bv    = (const float*)d_in[8];
  const float* Wlin  = (const float*)d_in[9];
  const float* wg    = (const float*)d_in[10];
  float* out = (float*)d_out;

  char* ws = (char*)d_ws;
  const size_t NQKV = (size_t)18432 * 1024;            // 37.75 MB as f16
  const size_t NVT  = (size_t)131072 * 160;            // padded vt (40 MB)
  // layout: [W 6MB][rp 128KB][qp][kp][vt 40MB][...path-specific]  (R3-proven)
  _Float16* Wqb = (_Float16*)(ws);
  _Float16* Wkb = (_Float16*)(ws + (2u << 20));
  _Float16* Wvb = (_Float16*)(ws + (4u << 20));
  float*    rp  = (float*)(ws + (6u << 20));
  _Float16* qp  = (_Float16*)(ws + (6u << 20) + 131072);
  _Float16* kp  = qp + NQKV;
  _Float16* vt  = kp + NQKV;                           // 40MB; written by gemm z==vtz

  dim3 agrid(3, 128);

  if (ws_size >= 238000000ull) {
    // parallel layout: all three f16 inputs live at once; ONE prep launch, one z=3 GEMM.
    _Float16* ia = vt + NVT + 32768;   // 64KB guard (attn tail prefetch overrun lands here)
    _Float16* ib = ia + NQKV;
    _Float16* ic = ib + NQKV;
    prep_all<<<29840, 256, 0, stream>>>(query, key, value, ia, ib, ic,
                                        Wq, Wk, Wv, Wqb, Wkb, Wvb,
                                        Wlin, wg, rp, vt);
    gemm_proj<<<dim3(8, 64, 3), 256, 0, stream>>>(ia, ib, ic, Wqb, Wkb, Wvb,
                                                  bq, bk, bv, qp, kp, kp /*unused z2*/,
                                                  vt, 2);
    attn_kernel<<<agrid, 256, 0, stream>>>(qp, kp, vt, rp, out);
  } else {
    // sequential layout: shared input buffer after vt.
    _Float16* inb = vt + NVT;          // also absorbs attn tail-prefetch overrun
    prep_small<<<2192, 256, 0, stream>>>(Wq, Wk, Wv, Wqb, Wkb, Wvb, Wlin, wg, rp, vt);
    conv3_f32_f16<<<dim3((int)(NQKV / 2048), 1, 1), 256, 0, stream>>>(
        query, query, query, inb, inb, inb, (int)NQKV);
    gemm_proj<<<dim3(8, 64, 1), 256, 0, stream>>>(inb, inb, inb, Wqb, Wqb, Wqb,
                                                  bq, bq, bq, qp, qp, qp, nullptr, -1);
    conv3_f32_f16<<<dim3((int)(NQKV / 2048), 1, 1), 256, 0, stream>>>(
        key, key, key, inb, inb, inb, (int)NQKV);
    gemm_proj<<<dim3(8, 64, 1), 256, 0, stream>>>(inb, inb, inb, Wkb, Wkb, Wkb,
                                                  bk, bk, bk, kp, kp, kp, nullptr, -1);
    conv3_f32_f16<<<dim3((int)(NQKV / 2048), 1, 1), 256, 0, stream>>>(
        value, value, value, inb, inb, inb, (int)NQKV);
    gemm_proj<<<dim3(8, 64, 1), 256, 0, stream>>>(inb, inb, inb, Wvb, Wvb, Wvb,
                                                  bv, bv, bv, qp /*unused*/, qp, qp,
                                                  vt, 0);
    attn_kernel<<<agrid, 256, 0, stream>>>(qp, kp, vt, rp, out);
  }
}

// Round 11
// 272.482 us; speedup vs baseline: 1.0919x; 1.0177x over previous
//
#include <hip/hip_runtime.h>
#include <hip/hip_fp16.h>

#define DEV __device__ __forceinline__

using half8 = __attribute__((ext_vector_type(8))) _Float16;
using half4 = __attribute__((ext_vector_type(4))) _Float16;
using f32x4 = __attribute__((ext_vector_type(4))) float;

// async global->LDS, 16B per lane. LDS dest is wave-uniform base + lane*16B.
DEV void gload_lds16(const void* g, void* l) {
  __builtin_amdgcn_global_load_lds((const __attribute__((address_space(1))) unsigned int*)g,
                                   (__attribute__((address_space(3))) unsigned int*)l,
                                   16, 0, 0);
}

DEV f32x4 mfma16x32(half8 a, half8 b, f32x4 c) {
  return __builtin_amdgcn_mfma_f32_16x16x32_f16(a, b, c, 0, 0, 0);
}

DEV void conv2048(const float* __restrict__ s, _Float16* __restrict__ d, int t) {
  int i = t * 8;
  float4 a = *(const float4*)(s + i);
  float4 b = *(const float4*)(s + i + 4);
  half8 h;
  h[0] = (_Float16)a.x; h[1] = (_Float16)a.y; h[2] = (_Float16)a.z; h[3] = (_Float16)a.w;
  h[4] = (_Float16)b.x; h[5] = (_Float16)b.y; h[6] = (_Float16)b.z; h[7] = (_Float16)b.w;
  *(half8*)(d + i) = h;
}

DEV void rp_body(const float* __restrict__ Wlin, const float* __restrict__ wg,
                 float* __restrict__ rp, int s, int t) {
  if (t >= 144) return;
  int rs = s / 12, cs = s % 12, rt = t / 12, ct = t % 12;
  float dx = (cs - ct) / 12.f, dy = (rs - rt) / 12.f;
  float ax = (dx > 0.f) ? 0.5f : (dx < 0.f ? -0.5f : 0.f);
  float ay = (dy > 0.f) ? 0.5f : (dy < 0.f ? -0.5f : 0.f);
  float lx = fabsf(logf(fabsf(dx) + 0.5f));
  float ly = fabsf(logf(fabsf(dy) + 0.5f));
  float a0 = 0.f, a1 = 0.f, a2 = 0.f, a3 = 0.f;
  const float* wgs = wg + s * 1024;
  for (int d = 0; d < 1024; d += 4) {
#pragma unroll
    for (int u = 0; u < 4; ++u) {
      float4 w = *(const float4*)(Wlin + (d + u) * 4);
      float dot = lx * w.x + ly * w.y + ax * w.z + ay * w.w;
      dot = dot > 0.f ? dot : 0.f;
      float p = dot * wgs[d + u];
      if (u == 0) a0 += p; else if (u == 1) a1 += p; else if (u == 2) a2 += p; else a3 += p;
    }
  }
  float acc = (a0 + a1) + (a2 + a3);
  rp[s * 144 + t] = acc > 0.f ? acc : 0.f;
}

// ---------------- prep_all: rp + vt_pad + conv(weights) + conv(Q,K,V) in ONE launch ---
//   [0,144) rp ; [144,656) vt pad ; [656,2192) conv weights ; [2192,29840) conv Q/K/V
__global__ void prep_all(const float* __restrict__ query, const float* __restrict__ key,
                         const float* __restrict__ value, _Float16* __restrict__ ia,
                         _Float16* __restrict__ ib, _Float16* __restrict__ ic,
                         const float* __restrict__ Wq, const float* __restrict__ Wk,
                         const float* __restrict__ Wv, _Float16* __restrict__ Wqb,
                         _Float16* __restrict__ Wkb, _Float16* __restrict__ Wvb,
                         const float* __restrict__ Wlin, const float* __restrict__ wg,
                         float* __restrict__ rp, _Float16* __restrict__ vt) {
  int id = blockIdx.x, t = threadIdx.x;
  if (id < 144) {
    rp_body(Wlin, wg, rp, id, t);
  } else if (id < 656) {
    int i = (id - 144) * 256 + t;                 // 131072 (b,e) rows
    _Float16* p = vt + (size_t)i * 160 + 144;
    *(half8*)p = (half8){};
    *(half8*)(p + 8) = (half8){};
  } else if (id < 2192) {
    int id3 = id - 656;
    int z = id3 >> 9, r = id3 & 511;              // 3 x 512 blocks, 2048 elems each
    const float* s = z == 0 ? Wq : (z == 1 ? Wk : Wv);
    _Float16* d = z == 0 ? Wqb : (z == 1 ? Wkb : Wvb);
    conv2048(s + r * 2048, d + r * 2048, t);
  } else {
    int id4 = id - 2192;
    int z = id4 / 9216, r = id4 % 9216;           // 3 x 9216 blocks, 2048 elems each
    const float* s = z == 0 ? query : (z == 1 ? key : value);
    _Float16* d = z == 0 ? ia : (z == 1 ? ib : ic);
    conv2048(s + (size_t)r * 2048, d + (size_t)r * 2048, t);
  }
}

// small-path prep (sequential layout): rp + vt_pad + conv weights only
__global__ void prep_small(const float* __restrict__ Wq, const float* __restrict__ Wk,
                           const float* __restrict__ Wv, _Float16* __restrict__ Wqb,
                           _Float16* __restrict__ Wkb, _Float16* __restrict__ Wvb,
                           const float* __restrict__ Wlin, const float* __restrict__ wg,
                           float* __restrict__ rp, _Float16* __restrict__ vt) {
  int id = blockIdx.x, t = threadIdx.x;
  if (id < 144) {
    rp_body(Wlin, wg, rp, id, t);
  } else if (id < 656) {
    int i = (id - 144) * 256 + t;
    _Float16* p = vt + (size_t)i * 160 + 144;
    *(half8*)p = (half8){};
    *(half8*)(p + 8) = (half8){};
  } else {
    int id3 = id - 656;
    int z = id3 >> 9, r = id3 & 511;
    const float* s = z == 0 ? Wq : (z == 1 ? Wk : Wv);
    _Float16* d = z == 0 ? Wqb : (z == 1 ? Wkb : Wvb);
    conv2048(s + r * 2048, d + r * 2048, t);
  }
}

// ---------------- f32 -> f16, 3 buffers in one launch (z selects; sequential path) ----
__global__ void conv3_f32_f16(const float* __restrict__ s0, const float* __restrict__ s1,
                              const float* __restrict__ s2, _Float16* __restrict__ d0,
                              _Float16* __restrict__ d1, _Float16* __restrict__ d2, int n) {
  const float* s = blockIdx.z == 0 ? s0 : (blockIdx.z == 1 ? s1 : s2);
  _Float16* d = blockIdx.z == 0 ? d0 : (blockIdx.z == 1 ? d1 : d2);
  int i = blockIdx.x * 2048;
  if (i >= n) return;
  conv2048(s + i, d + i, (int)threadIdx.x);
}

// ---------------- projection GEMM: C = relu(A * B^T + bias), f16 in/out ----------------
// 288(M)x128(N) block, 4 waves (2x2), wave-tile 144x64 (acc 9x4), BK=32.  (R10-proven)
// 26 chunks/slot (A 18 + B 8); waves 0,1 stage 7 chunks, waves 2,3 stage 6 ->
// per-wave counted vmcnt(7)/vmcnt(6). 26KB slots x3 = 78KB -> 2 blocks/CU.
// Per-z grid 512 blocks, total 1536 = exactly 3 rounds of 512 resident.
// z == vtz writes the TRANSPOSED output into vt[(b*1024+e)*160+s].
__global__ __launch_bounds__(256, 2) void gemm_proj(
    const _Float16* __restrict__ a0q, const _Float16* __restrict__ a1q,
    const _Float16* __restrict__ a2q, const _Float16* __restrict__ w0q,
    const _Float16* __restrict__ w1q, const _Float16* __restrict__ w2q,
    const float* __restrict__ bi0, const float* __restrict__ bi1,
    const float* __restrict__ bi2, _Float16* __restrict__ c0q,
    _Float16* __restrict__ c1q, _Float16* __restrict__ c2q,
    _Float16* __restrict__ vtp, int vtz) {
  const _Float16* A = blockIdx.z == 0 ? a0q : (blockIdx.z == 1 ? a1q : a2q);
  const _Float16* W = blockIdx.z == 0 ? w0q : (blockIdx.z == 1 ? w1q : w2q);
  const float* bias = blockIdx.z == 0 ? bi0 : (blockIdx.z == 1 ? bi1 : bi2);
  _Float16* C = blockIdx.z == 0 ? c0q : (blockIdx.z == 1 ? c1q : c2q);

  __shared__ __align__(16) char lds[79872];  // 3 x 26KB slots (A 18KB + B 8KB each)
  int tid = threadIdx.x, wid = tid >> 6, lane = tid & 63;
  int lin = blockIdx.y * 8 + blockIdx.x;     // 0..511 per z ; XCD-chunked, 64 per XCD
  int local = lin >> 3;                      // 0..63
  int mt = (lin & 7) * 8 + (local >> 3), nt = local & 7;   // mt 0..63, nt 0..7
  int m0 = mt * 288, n0 = nt * 128;

  int r4l = lane >> 2, c4 = lane & 3;
  int cg8 = ((c4 + (r4l >> 1)) & 3) * 8;                 // rotated source kslot (f16)
  int lr = lane & 15, lg = lane >> 4;
  int rdoff = lr * 64 + ((lg - (lr >> 1)) & 3) * 16;     // fragment read offset (bytes)

  // 26 chunks: 0..17 A rows m0+q*16, 18..25 B rows n0+(q-18)*16. Wave w stages c*4+w.
  const _Float16* gp[7];
#pragma unroll
  for (int c = 0; c < 7; ++c) {
    int q = c * 4 + wid;
    if (q < 26)
      gp[c] = (q < 18) ? A + (size_t)(m0 + q * 16 + r4l) * 1024 + cg8
                       : W + (size_t)(n0 + (q - 18) * 16 + r4l) * 1024 + cg8;
    else
      gp[c] = A;  // unused
  }
  char *sl0 = lds, *sl1 = lds + 26624, *sl2 = lds + 53248;
  auto issue = [&](char* slot) {
#pragma unroll
    for (int c = 0; c < 7; ++c) {
      if (c * 4 + wid < 26) { gload_lds16(gp[c], slot + (c * 4 + wid) * 1024); gp[c] += 32; }
    }
  };
  issue(sl0);
  issue(sl1);
  f32x4 acc[9][4] = {};
  int abase = (wid >> 1) * 9216, bbase = 18432 + (wid & 1) * 4096;
  for (int t = 0; t < 32; ++t) {
    // per-wave counted vmcnt: retires exactly the slot consumed this iteration
    if (wid < 2) asm volatile("s_waitcnt vmcnt(7)" ::: "memory");
    else         asm volatile("s_waitcnt vmcnt(6)" ::: "memory");
    __builtin_amdgcn_s_barrier();
    __builtin_amdgcn_sched_barrier(0);
    issue(sl2);  // unconditional; tail prefetch reads in-bounds garbage (ws interior)
    half8 a[9], b[4];
#pragma unroll
    for (int i = 0; i < 9; ++i) a[i] = *(const half8*)(sl0 + abase + i * 1024 + rdoff);
#pragma unroll
    for (int j = 0; j < 4; ++j) b[j] = *(const half8*)(sl0 + bbase + j * 1024 + rdoff);
#pragma unroll
    for (int i = 0; i < 9; ++i)
#pragma unroll
      for (int j = 0; j < 4; ++j)
        acc[i][j] = mfma16x32(b[j], a[i], acc[i][j]);  // swapped: lane holds 4 consec cols
    char* tmp = sl0; sl0 = sl1; sl1 = sl2; sl2 = tmp;
  }
  // epilogue: bias + relu -> f16. Normal z: 8B vector stores to C.
  // z == vtz: transposed scatter into vt (16-consecutive-s x 2B = 32B segments).
  int wm = (wid >> 1) * 144, wn = (wid & 1) * 64;
  bool tov = (vtp != nullptr) && ((int)blockIdx.z == vtz);
#pragma unroll
  for (int i = 0; i < 9; ++i) {
    int row = m0 + wm + i * 16 + lr;
#pragma unroll
    for (int j = 0; j < 4; ++j) {
      int col = n0 + wn + j * 16 + lg * 4;
      float4 b4 = *(const float4*)(bias + col);
      half4 h;
      float v0 = acc[i][j][0] + b4.x; h[0] = (_Float16)(v0 > 0.f ? v0 : 0.f);
      float v1 = acc[i][j][1] + b4.y; h[1] = (_Float16)(v1 > 0.f ? v1 : 0.f);
      float v2 = acc[i][j][2] + b4.z; h[2] = (_Float16)(v2 > 0.f ? v2 : 0.f);
      float v3 = acc[i][j][3] + b4.w; h[3] = (_Float16)(v3 > 0.f ? v3 : 0.f);
      if (tov) {
        int bb = row / 144, ss = row - bb * 144;
        _Float16* vb = vtp + (size_t)(bb * 1024 + col) * 160 + ss;
        vb[0] = h[0]; vb[160] = h[1]; vb[320] = h[2]; vb[480] = h[3];
      } else {
        *(half4*)(C + (size_t)row * 1024 + col) = h;
      }
    }
  }
}

// ---------------- attn1: QK^T + rp + softmax -> P (f16) + sums exported to global ----
// q,k [18432][1024] f16 ; rp [144][144] f32. Pg[(b*3+third)*48*160], sums_g[bt*48].
// Phase-1 body byte-identical to the proven monolithic attn.
__global__ __launch_bounds__(256) void attn1_kernel(const _Float16* __restrict__ q,
                                                    const _Float16* __restrict__ k,
                                                    const float* __restrict__ rp,
                                                    _Float16* __restrict__ Pg,
                                                    float* __restrict__ sums_g) {
  __shared__ __align__(16) char lds[53248];
  float* sc = (float*)lds;
  _Float16* P = (_Float16*)(lds + 36864);
  float* sums = (float*)(lds + 52992);

  int tid = threadIdx.x, wid = tid >> 6, lane = tid & 63;
  int lin = blockIdx.y * 3 + blockIdx.x;       // 0..383
  int swz = (lin & 7) * 48 + (lin >> 3);
  int mt3 = swz % 3, b = swz / 3;
  int m0 = mt3 * 48;
  const int nstart_t[4] = {0, 3, 5, 7};
  const int ncnt_t[4]   = {3, 2, 2, 2};
  int ns = nstart_t[wid], nc = ncnt_t[wid];
  int r4l = lane >> 2, c4 = lane & 3;
  int cg8 = ((c4 + (r4l >> 1)) & 3) * 8;
  int lr = lane & 15, lg = lane >> 4;
  int rdoff = lr * 64 + ((lg - (lr >> 1)) & 3) * 16;   // bytes

  // ---- phase 1: scores = q . k^T over K=1024, triple-buffer depth-2 ----
  {
    char *sl0 = lds, *sl1 = lds + 12288, *sl2 = lds + 24576;
    const _Float16* g1[3];
#pragma unroll
    for (int c = 0; c < 3; ++c) {
      int qq = c * 4 + wid;  // 0..2 -> q chunks (48 rows), 3..11 -> k chunks (144 rows)
      g1[c] = (qq < 3) ? q + (size_t)(b * 144 + m0 + qq * 16 + r4l) * 1024 + cg8
                       : k + (size_t)(b * 144 + (qq - 3) * 16 + r4l) * 1024 + cg8;
    }
    auto issue1 = [&](char* slot) {
#pragma unroll
      for (int c = 0; c < 3; ++c) {
        gload_lds16(g1[c], slot + (c * 4 + wid) * 1024);
        g1[c] += 32;
      }
    };
    issue1(sl0);
    issue1(sl1);
    f32x4 acc[3][3] = {};
    for (int t = 0; t < 32; ++t) {
      asm volatile("s_waitcnt vmcnt(3)" ::: "memory");
      __builtin_amdgcn_sched_barrier(0);
      __builtin_amdgcn_s_barrier();
      __builtin_amdgcn_sched_barrier(0);
      issue1(sl2);  // tail garbage stays inside readable ws
      half8 af[3], bf[3];
#pragma unroll
      for (int i = 0; i < 3; ++i)
        af[i] = *(const half8*)(sl0 + i * 1024 + rdoff);
#pragma unroll
      for (int j = 0; j < 3; ++j)
        if (j < nc)
          bf[j] = *(const half8*)(sl0 + (3 + ns + j) * 1024 + rdoff);
#pragma unroll
      for (int i = 0; i < 3; ++i)
#pragma unroll
        for (int j = 0; j < 3; ++j)
          if (j < nc)
            acc[i][j] = mfma16x32(bf[j], af[i], acc[i][j]);  // swapped
      char* tmp = sl0; sl0 = sl1; sl1 = sl2; sl2 = tmp;
    }
    asm volatile("s_waitcnt vmcnt(0)" ::: "memory");
    __syncthreads();  // straggler prefetches drained before sc aliases the slots
    const float scale = 0.03125f;  // 1024^-0.5
#pragma unroll
    for (int i = 0; i < 3; ++i) {
      int qrow = i * 16 + lr;
#pragma unroll
      for (int j = 0; j < 3; ++j)
        if (j < nc) {
          int kc0 = (ns + j) * 16 + lg * 4;
          float4 rr = *(const float4*)(rp + (m0 + qrow) * 144 + kc0);
          f32x4 vs;
          vs[0] = acc[i][j][0] * scale + rr.x;
          vs[1] = acc[i][j][1] * scale + rr.y;
          vs[2] = acc[i][j][2] * scale + rr.z;
          vs[3] = acc[i][j][3] * scale + rr.w;
          *(f32x4*)(sc + qrow * 152 + kc0) = vs;
        }
    }
  }
  __syncthreads();

  // ---- softmax (unnormalized; sums kept for attn_pv) ----
  if (tid < 192) {
    int r = tid >> 2, qd = tid & 3;
    int cb = qd * 36;
    float m = -1e30f;
    for (int c2 = 0; c2 < 36; ++c2) m = fmaxf(m, sc[r * 152 + cb + c2]);
    m = fmaxf(m, __shfl_xor(m, 1));
    m = fmaxf(m, __shfl_xor(m, 2));
    float s = 0.f;
    for (int c2 = 0; c2 < 36; ++c2) {
      float e = __expf(sc[r * 152 + cb + c2] - m);
      s += e;
      P[r * 168 + cb + c2] = (_Float16)e;
    }
    s += __shfl_xor(s, 1);
    s += __shfl_xor(s, 2);
    if (qd == 0) sums[r] = s;
  }
  if (tid < 96) {  // zero-pad P cols 144..159
    int r = tid >> 1, c0 = 144 + (tid & 1) * 8;
    *(half8*)(P + r * 168 + c0) = (half8){};
  }
  __syncthreads();

  // ---- export P (48x160, LDS stride 168 -> global stride 160) + sums ----
  {
    int bt = b * 3 + mt3;
    _Float16* Pgb = Pg + (size_t)bt * 48 * 160;
    for (int idx = tid; idx < 960; idx += 256) {     // 48 rows x 20 half8-chunks
      int r = idx / 20, c = idx % 20;
      *(half8*)(Pgb + r * 160 + c * 8) = *(const half8*)(P + r * 168 + c * 8);
    }
    if (tid < 48) sums_g[bt * 48 + tid] = sums[tid];
  }
}

// ---------------- attn_pv: out = (P @ V) / sums, one block per (bt, 256-col quarter) --
// 1536 blocks, 32KB LDS -> 5 blocks/CU (vs 1.5 for monolithic attn): TLP covers the
// vmcnt(0)+barrier drains. Staging/fragment machinery identical to the proven phase-2.
__global__ __launch_bounds__(256) void attn_pv(const _Float16* __restrict__ Pg,
                                               const float* __restrict__ sums_g,
                                               const _Float16* __restrict__ vt,
                                               float* __restrict__ out) {
  __shared__ __align__(16) char lds[32768];
  int tid = threadIdx.x, wid = tid >> 6, lane = tid & 63;
  int lin = blockIdx.y * 12 + blockIdx.x;      // 0..1535
  int swz = (lin & 7) * 192 + (lin >> 3);      // XCD-chunked (1536 = 8*192, bijective)
  int bt = swz >> 2, nq = swz & 3;
  int b = bt / 3, m0 = (bt % 3) * 48;
  int r4l = lane >> 2, c4 = lane & 3;
  int cg8 = ((c4 + (r4l >> 1)) & 3) * 8;
  int lr = lane & 15, lg = lane >> 4;
  int rdoff = lr * 64 + ((lg - (lr >> 1)) & 3) * 16;   // bytes

  char *s0p = lds, *s1p = lds + 16384;
  auto issue = [&](int it, char* slot) {
#pragma unroll
    for (int c = 0; c < 4; ++c) {
      int ch = c * 4 + wid;  // 16 chunks = 256 e-rows of vt
      gload_lds16(vt + (size_t)(b * 1024 + nq * 256 + ch * 16 + r4l) * 160 + it * 32 + cg8,
                  slot + ch * 1024);
    }
  };
  issue(0, s0p);
  f32x4 o[3][4] = {};
  for (int it = 0; it < 5; ++it) {
    asm volatile("s_waitcnt vmcnt(0)" ::: "memory");
    __builtin_amdgcn_sched_barrier(0);
    __builtin_amdgcn_s_barrier();
    __builtin_amdgcn_sched_barrier(0);
    if (it < 4) issue(it + 1, (it & 1) ? s0p : s1p);
    char* sb = (it & 1) ? s1p : s0p;
    int k0 = it * 32;
    half8 af[3], bf[4];
#pragma unroll
    for (int i = 0; i < 3; ++i)
      af[i] = *(const half8*)(Pg + ((size_t)bt * 48 + i * 16 + lr) * 160 + k0 + lg * 8);
#pragma unroll
    for (int j = 0; j < 4; ++j)
      bf[j] = *(const half8*)(sb + (wid * 4 + j) * 1024 + rdoff);
#pragma unroll
    for (int i = 0; i < 3; ++i)
#pragma unroll
      for (int j = 0; j < 4; ++j)
        o[i][j] = mfma16x32(bf[j], af[i], o[i][j]);  // swapped
  }
#pragma unroll
  for (int i = 0; i < 3; ++i) {
    int row = i * 16 + lr;
    float inv = 1.f / sums_g[bt * 48 + row];
#pragma unroll
    for (int j = 0; j < 4; ++j) {
      f32x4 vo;
      vo[0] = o[i][j][0] * inv; vo[1] = o[i][j][1] * inv;
      vo[2] = o[i][j][2] * inv; vo[3] = o[i][j][3] * inv;
      *(f32x4*)(out + (size_t)(b * 144 + m0 + row) * 1024 + nq * 256 + wid * 64 + j * 16 + lg * 4) = vo;
    }
  }
}

extern "C" void kernel_launch(void* const* d_in, const int* in_sizes, int n_in,
                              void* d_out, int out_size, void* d_ws, size_t ws_size,
                              hipStream_t stream) {
  const float* query = (const float*)d_in[0];
  const float* key   = (const float*)d_in[1];
  const float* value = (const float*)d_in[2];
  const float* Wq    = (const float*)d_in[3];
  const float* bq    = (const float*)d_in[4];
  const float* Wk    = (const float*)d_in[5];
  const float* bk    = (const float*)d_in[6];
  const float* Wv    = (const float*)d_in[7];
  const float* bv    = (const float*)d_in[8];
  const float* Wlin  = (const float*)d_in[9];
  const float* wg    = (const float*)d_in[10];
  float* out = (float*)d_out;

  char* ws = (char*)d_ws;
  const size_t NQKV = (size_t)18432 * 1024;            // 37.75 MB as f16
  const size_t NVT  = (size_t)131072 * 160;            // padded vt (40 MB)
  // layout: [W 6MB][rp 128KB][qp][kp][vt 40MB][...path-specific]  (R3-proven)
  _Float16* Wqb = (_Float16*)(ws);
  _Float16* Wkb = (_Float16*)(ws + (2u << 20));
  _Float16* Wvb = (_Float16*)(ws + (4u << 20));
  float*    rp  = (float*)(ws + (6u << 20));
  _Float16* qp  = (_Float16*)(ws + (6u << 20) + 131072);
  _Float16* kp  = qp + NQKV;
  _Float16* vt  = kp + NQKV;                           // 40MB; written by gemm z==vtz

  dim3 a1grid(3, 128), pvgrid(12, 128);

  if (ws_size >= 238000000ull) {
    // parallel layout: ONE prep launch, one z=3 GEMM, split attention.
    _Float16* ia = vt + NVT + 32768;   // 64KB guard (attn tail prefetch overrun lands here)
    _Float16* ib = ia + NQKV;
    _Float16* ic = ib + NQKV;
    // Pg/sums reuse ia's region (dead after gemm): 5.9MB + 74KB << 37.75MB
    _Float16* Pg = ia;
    float* sums_g = (float*)((char*)ia + (6u << 20));
    prep_all<<<29840, 256, 0, stream>>>(query, key, value, ia, ib, ic,
                                        Wq, Wk, Wv, Wqb, Wkb, Wvb,
                                        Wlin, wg, rp, vt);
    gemm_proj<<<dim3(8, 64, 3), 256, 0, stream>>>(ia, ib, ic, Wqb, Wkb, Wvb,
                                                  bq, bk, bv, qp, kp, kp /*unused z2*/,
                                                  vt, 2);
    attn1_kernel<<<a1grid, 256, 0, stream>>>(qp, kp, rp, Pg, sums_g);
    attn_pv<<<pvgrid, 256, 0, stream>>>(Pg, sums_g, vt, out);
  } else {
    // sequential layout: shared input buffer after vt (dead after last gemm -> Pg).
    _Float16* inb = vt + NVT;          // also absorbs attn tail-prefetch overrun
    _Float16* Pg = inb;
    float* sums_g = (float*)((char*)inb + (6u << 20));
    prep_small<<<2192, 256, 0, stream>>>(Wq, Wk, Wv, Wqb, Wkb, Wvb, Wlin, wg, rp, vt);
    conv3_f32_f16<<<dim3((int)(NQKV / 2048), 1, 1), 256, 0, stream>>>(
        query, query, query, inb, inb, inb, (int)NQKV);
    gemm_proj<<<dim3(8, 64, 1), 256, 0, stream>>>(inb, inb, inb, Wqb, Wqb, Wqb,
                                                  bq, bq, bq, qp, qp, qp, nullptr, -1);
    conv3_f32_f16<<<dim3((int)(NQKV / 2048), 1, 1), 256, 0, stream>>>(
        key, key, key, inb, inb, inb, (int)NQKV);
    gemm_proj<<<dim3(8, 64, 1), 256, 0, stream>>>(inb, inb, inb, Wkb, Wkb, Wkb,
                                                  bk, bk, bk, kp, kp, kp, nullptr, -1);
    conv3_f32_f16<<<dim3((int)(NQKV / 2048), 1, 1), 256, 0, stream>>>(
        value, value, value, inb, inb, inb, (int)NQKV);
    gemm_proj<<<dim3(8, 64, 1), 256, 0, stream>>>(inb, inb, inb, Wvb, Wvb, Wvb,
                                                  bv, bv, bv, qp /*unused*/, qp, qp,
                                                  vt, 0);
    attn1_kernel<<<a1grid, 256, 0, stream>>>(qp, kp, rp, Pg, sums_g);
    attn_pv<<<pvgrid, 256, 0, stream>>>(Pg, sums_g, vt, out);
  }
}